// Round 11
// baseline (726.123 us; speedup 1.0000x reference)
//
#include <hip/hip_runtime.h>

#define N_NODES 100000
#define N_EDGES 6400000
#define IN_CH   128
#define HID     32
#define QT      800000          // floats per quarter table (100000 nodes x 8 ch)

#define BKT_SHIFT 9
#define BKT_MASK  511
#define BKT_SZ    512
#define NBKT      196           // ceil(100000/512)
#define NBLK      1024          // histogram/scatter tiles
#define TILE      6250          // 6.4M / 1024 exactly
#define QMAX      8704          // quarter-bucket LDS staging capacity

// ---------- ws layout (bytes) ----------
// [0, 25.6M): ebuf during build; then A0=hsq/hs2q, A1=h1q/h2q quarter tables
#define O_EBUF 0u
#define O_A0   0u               // hsq (conv1 in), later hs2q (conv2 in)
#define O_A1   12800000u        // h1q (conv1 out), later h2q (conv2 out)
// ghist int[1024*196]=802,816 (hist->scatter); gh2 ushort overlay (sort2a->b)
#define O_GH   25600000u
// cursors (scan3->scatter) then csr32 (sort2b->aggs) overlay
#define O_CUR  26402816u
#define O_CSR  26402816u        // int[6.4M] -> ends 52,002,816
#define O_ROWS 52002816u        // (N_NODES+1)*4
#define O_BST  52402824u
#define O_BTOT 52403616u
#define O_FLAG 52404400u
// total ~52.40 MB (<= 52.80 MB proven in R1)

// Detect whether edge_index buffer is int64 (high words all zero) or int32.
__global__ void k_detect(const unsigned int* e, int* flag) {
    __shared__ int any;
    if (threadIdx.x == 0) any = 0;
    __syncthreads();
    int acc = 0;
    for (int i = threadIdx.x; i < 4096; i += 256)
        acc |= (e[2 * i + 1] != 0u);
    if (acc) atomicOr(&any, 1);
    __syncthreads();
    if (threadIdx.x == 0) *flag = any ? 0 : 1;   // 1 => int64
}

// Non-temporal streaming edge load (wave-coalesced, read-once). LOADS ONLY.
__device__ __forceinline__ int eload_nt(const int* e, int is64, long long idx) {
    return is64 ? (int)__builtin_nontemporal_load((const long long*)e + idx)
                : __builtin_nontemporal_load(e + (size_t)idx);
}

// Per-tile histogram over destination buckets (LDS int atomics only).
__global__ void k_hist(const int* e, const int* flag, int* ghist) {
    __shared__ int h[NBKT];
    for (int i = threadIdx.x; i < NBKT; i += 256) h[i] = 0;
    __syncthreads();
    int is64 = *flag;
    long long base = (long long)blockIdx.x * TILE;
    for (int k = threadIdx.x; k < TILE; k += 256) {
        int dst = eload_nt(e, is64, (long long)N_EDGES + base + k);
        atomicAdd(&h[dst >> BKT_SHIFT], 1);
    }
    __syncthreads();
    int* g = ghist + blockIdx.x * NBKT;
    for (int i = threadIdx.x; i < NBKT; i += 256) g[i] = h[i];
}

// btot[j] = sum over tiles of ghist[blk][j]; one block per bucket, wave reduce.
__global__ void k_scan1(const int* __restrict__ ghist, int* __restrict__ btot) {
    int j = blockIdx.x;
    int t = threadIdx.x;             // 64 threads
    int s = 0;
    for (int blk = t; blk < NBLK; blk += 64) s += ghist[blk * NBKT + j];
#pragma unroll
    for (int off = 32; off; off >>= 1) s += __shfl_down(s, off, 64);
    if (t == 0) btot[j] = s;
}

__global__ void k_scan2(const int* __restrict__ btot, int* __restrict__ bstart) {
    __shared__ int s[1024];
    int t = threadIdx.x;
    int v = (t < NBKT) ? btot[t] : 0;
    s[t] = v;
    __syncthreads();
    for (int off = 1; off < 1024; off <<= 1) {
        int u = (t >= off) ? s[t - off] : 0;
        __syncthreads();
        s[t] += u;
        __syncthreads();
    }
    if (t < NBKT) bstart[t] = s[t] - v;
    if (t == 0) bstart[NBKT] = N_EDGES;
}

__global__ void k_scan3(const int* __restrict__ ghist, const int* __restrict__ bstart,
                        int* __restrict__ cursors) {
    int j = blockIdx.x * 256 + threadIdx.x;
    if (j >= NBKT) return;
    int run = bstart[j];
    for (int blk = 0; blk < NBLK; ++blk) {
        cursors[blk * NBKT + j] = run;
        run += ghist[blk * NBKT + j];
    }
}

// Scatter: local counting sort in LDS, then burst copy-out (full-line runs).
__launch_bounds__(512)
__global__ void k_scatter(const int* e, const int* flag,
                          const int* __restrict__ ghist, const int* __restrict__ cursors,
                          unsigned int* __restrict__ ebuf) {
    __shared__ unsigned obuf[TILE];          // 25,000 B
    __shared__ unsigned char bid[TILE];      //  6,250 B
    __shared__ int lcur[NBKT];
    __shared__ int gbase[NBKT];
    __shared__ int wsum[8];
    int t = threadIdx.x;
    int blk = blockIdx.x;
    {
        int v = (t < NBKT) ? ghist[blk * NBKT + t] : 0;
        int lane = t & 63, w = t >> 6;
        int p = v;
#pragma unroll
        for (int off = 1; off < 64; off <<= 1) {
            int u = __shfl_up(p, off, 64);
            if (lane >= off) p += u;
        }
        if (lane == 63) wsum[w] = p;
        __syncthreads();
        int woff = 0;
        for (int k = 0; k < w; ++k) woff += wsum[k];
        int excl = woff + p - v;
        if (t < NBKT) {
            lcur[t]  = excl;
            gbase[t] = cursors[blk * NBKT + t] - excl;
        }
    }
    __syncthreads();
    int is64 = *flag;
    long long base = (long long)blk * TILE;
    for (int k = t; k < TILE; k += 512) {
        int src = eload_nt(e, is64, base + k);
        int dst = eload_nt(e, is64, (long long)N_EDGES + base + k);
        int b = dst >> BKT_SHIFT;
        int pos = atomicAdd(&lcur[b], 1);
        obuf[pos] = ((unsigned)src << BKT_SHIFT) | (unsigned)(dst & BKT_MASK);
        bid[pos] = (unsigned char)b;
    }
    __syncthreads();
    for (int i = t; i < TILE; i += 512) {
        int b = bid[i];
        ebuf[gbase[b] + i] = obuf[i];        // consecutive i -> consecutive addr
    }
}

// sort2a: per (bucket, quarter) histogram of dst-local bins -> gh2 (ushort).
__launch_bounds__(512)
__global__ void k_sort2a(const unsigned int* __restrict__ ebuf, const int* __restrict__ bstart,
                         unsigned short* __restrict__ gh2) {
    __shared__ int hist[BKT_SZ];
    int b = blockIdx.x >> 2, q = blockIdx.x & 3;
    int s0 = bstart[b], e0 = bstart[b + 1], len = e0 - s0;
    int lo = s0 + (int)((long long)len * q / 4);
    int hi = s0 + (int)((long long)len * (q + 1) / 4);
    hist[threadIdx.x] = 0;
    __syncthreads();
    for (int i = lo + (int)threadIdx.x; i < hi; i += 512)
        atomicAdd(&hist[__builtin_nontemporal_load(&ebuf[i]) & BKT_MASK], 1);
    __syncthreads();
    gh2[(b * 4 + q) * BKT_SZ + threadIdx.x] = (unsigned short)hist[threadIdx.x];
}

// sort2b: per (bucket, quarter) — scan bucket bins from 4 quarter-hists, then
// LDS counting sort of this quarter + burst copy-out.
__launch_bounds__(512)
__global__ void k_sort2b(const unsigned int* __restrict__ ebuf, const int* __restrict__ bstart,
                         const unsigned short* __restrict__ gh2, int* __restrict__ csr,
                         int* __restrict__ rows) {
    __shared__ unsigned obuf[QMAX];          // 34,816 B
    __shared__ unsigned short bid[QMAX];     // 17,408 B
    __shared__ int lcur[BKT_SZ];             // 2 KB
    __shared__ int gbase[BKT_SZ];            // 2 KB
    __shared__ int wsA[8], wsB[8];
    int b = blockIdx.x >> 2, q = blockIdx.x & 3;
    int s0 = bstart[b], e0 = bstart[b + 1], len = e0 - s0;
    int lo = s0 + (int)((long long)len * q / 4);
    int hi = s0 + (int)((long long)len * (q + 1) / 4);
    int t = threadIdx.x;                     // t == bin id
    int h0 = gh2[(b * 4 + 0) * BKT_SZ + t];
    int h1 = gh2[(b * 4 + 1) * BKT_SZ + t];
    int h2 = gh2[(b * 4 + 2) * BKT_SZ + t];
    int h3 = gh2[(b * 4 + 3) * BKT_SZ + t];
    int tot = h0 + h1 + h2 + h3;
    int hq = (q == 0) ? h0 : (q == 1) ? h1 : (q == 2) ? h2 : h3;
    int lane = t & 63, w = t >> 6;
    int p1 = tot, p2 = hq;
#pragma unroll
    for (int off = 1; off < 64; off <<= 1) {
        int u1 = __shfl_up(p1, off, 64);
        int u2 = __shfl_up(p2, off, 64);
        if (lane >= off) { p1 += u1; p2 += u2; }
    }
    if (lane == 63) { wsA[w] = p1; wsB[w] = p2; }
    __syncthreads();
    int woffA = 0, woffB = 0;
    for (int k = 0; k < w; ++k) { woffA += wsA[k]; woffB += wsB[k]; }
    int binstart = s0 + woffA + p1 - tot;    // bucket-wide bin start
    int lexcl    = woffB + p2 - hq;          // this quarter's local packed offset
    int qs = binstart + ((q > 0) ? h0 : 0) + ((q > 1) ? h1 : 0) + ((q > 2) ? h2 : 0);
    lcur[t]  = lexcl;
    gbase[t] = qs - lexcl;
    int node = b * BKT_SZ + t;
    if (q == 0 && node <= N_NODES) rows[node] = binstart;
    __syncthreads();
    for (int i = lo + t; i < hi; i += 512) {
        unsigned v = __builtin_nontemporal_load(&ebuf[i]);
        int bin = v & BKT_MASK;
        int pos = atomicAdd(&lcur[bin], 1);
        obuf[pos] = v >> BKT_SHIFT;
        bid[pos] = (unsigned short)bin;
    }
    __syncthreads();
    int qlen = hi - lo;
    for (int i = t; i < qlen; i += 512) {
        int bn = bid[i];
        csr[gbase[bn] + i] = (int)obuf[i];   // consecutive i -> consecutive addr
    }
}

// gemm1: hsq[q][i][c8] = dinv[i] * sum_k x[i][k] * W1[k][8q+c8]  (quartered out)
__launch_bounds__(256)
__global__ void k_gemm1(const float* __restrict__ x, const float* __restrict__ W1,
                        const int* __restrict__ rows, float* __restrict__ hsq) {
    __shared__ float w[IN_CH * HID];
    __shared__ float xs[8 * IN_CH];
    __shared__ float hstage[8][HID];
    for (int i = threadIdx.x; i < IN_CH * HID; i += 256) w[i] = W1[i];
    const float4* xb = (const float4*)(x + (size_t)blockIdx.x * 8 * IN_CH);
    ((float4*)xs)[threadIdx.x] = xb[threadIdx.x];
    __syncthreads();
    int lane = threadIdx.x & 31, hw = threadIdx.x >> 5;
    int node = blockIdx.x * 8 + hw;
    float dv = rsqrtf((float)(rows[node + 1] - rows[node] + 1));
    const float* xr = xs + hw * IN_CH;
    float acc = 0.f;
#pragma unroll
    for (int k = 0; k < IN_CH; ++k) acc += xr[k] * w[k * HID + lane];
    hstage[hw][lane] = acc * dv;
    __syncthreads();
    int q = threadIdx.x >> 6, k2 = threadIdx.x & 63;   // coalesced 256B per table
    hsq[(size_t)q * QT + blockIdx.x * 64 + k2] = hstage[k2 >> 3][q * 8 + (k2 & 7)];
}

// One channel-quarter aggregation pass. Wave = node; 8 lanes per edge.
// tq: L2-resident 3.2MB quarter table. csr/rows via nt loads (no L2 pollution).
// outq[node][c8] = relu(dv * (self + sum_src tq[src][c8]) + bias[c8])
__launch_bounds__(512)
__global__ void k_aggpass(const float* __restrict__ tq, const int* __restrict__ csr,
                          const int* __restrict__ rows, const float* __restrict__ bias,
                          float* __restrict__ outq) {
    __shared__ float stage[8][8];
    int tid = threadIdx.x;
    int wv = tid >> 6, lane = tid & 63;
    int eg = lane >> 3, c = lane & 7;
    int node = blockIdx.x * 8 + wv;
    int r0 = rows[node], r1 = rows[node + 1];
    float dv = rsqrtf((float)(r1 - r0 + 1));
    float acc = 0.f;
    int j = r0 + eg;
    for (; j + 24 < r1; j += 32) {           // 4 gathers in flight per group
        int i0 = __builtin_nontemporal_load(csr + j);
        int i1 = __builtin_nontemporal_load(csr + j + 8);
        int i2 = __builtin_nontemporal_load(csr + j + 16);
        int i3 = __builtin_nontemporal_load(csr + j + 24);
        float f0 = tq[i0 * 8 + c];
        float f1 = tq[i1 * 8 + c];
        float f2 = tq[i2 * 8 + c];
        float f3 = tq[i3 * 8 + c];
        acc += (f0 + f1) + (f2 + f3);
    }
    for (; j < r1; j += 8)
        acc += tq[__builtin_nontemporal_load(csr + j) * 8 + c];
#pragma unroll
    for (int off = 8; off < 64; off <<= 1)   // reduce across 8 edge-groups
        acc += __shfl_xor(acc, off, 64);
    acc += tq[node * 8 + c];                 // self loop
    float v = fmaxf(acc * dv + bias[c], 0.f);
    if (lane < 8) stage[wv][c] = v;
    __syncthreads();
    if (tid < 64)                            // one coalesced 256B nt burst
        __builtin_nontemporal_store(stage[tid >> 3][tid & 7],
                                    outq + (size_t)blockIdx.x * 64 + tid);
}

// gemm2: hs2q[q][i][c8] = dinv[i] * sum_k h1[i][k] * W2[k][8q+c8]
__launch_bounds__(256)
__global__ void k_gemm2(const float* __restrict__ h1q, const float* __restrict__ W2,
                        const int* __restrict__ rows, float* __restrict__ hs2q) {
    __shared__ float w2[HID * HID];
    __shared__ float h1s[8][HID];
    __shared__ float hstage[8][HID];
    for (int i = threadIdx.x; i < HID * HID; i += 256) w2[i] = W2[i];
    int lane = threadIdx.x & 31, hw = threadIdx.x >> 5;
    int node = blockIdx.x * 8 + hw;
    h1s[hw][lane] = h1q[(size_t)(lane >> 3) * QT + node * 8 + (lane & 7)];
    __syncthreads();
    float dv = rsqrtf((float)(rows[node + 1] - rows[node] + 1));
    float g = 0.f;
#pragma unroll
    for (int k = 0; k < HID; ++k) g += h1s[hw][k] * w2[k * HID + lane];
    hstage[hw][lane] = g * dv;
    __syncthreads();
    int q = threadIdx.x >> 6, k2 = threadIdx.x & 63;
    hs2q[(size_t)q * QT + blockIdx.x * 64 + k2] = hstage[k2 >> 3][q * 8 + (k2 & 7)];
}

// head: out = relu(h2 @ Wl1 + bl1) @ Wl2 + bl2
__launch_bounds__(256)
__global__ void k_head(const float* __restrict__ h2q, const float* __restrict__ Wl1,
                       const float* __restrict__ bl1, const float* __restrict__ Wl2,
                       const float* __restrict__ bl2, float* __restrict__ out) {
    __shared__ float wl1[HID * HID];
    __shared__ float h2s[8][HID];
    for (int i = threadIdx.x; i < HID * HID; i += 256) wl1[i] = Wl1[i];
    int lane = threadIdx.x & 31, hw = threadIdx.x >> 5;
    int node = blockIdx.x * 8 + hw;
    h2s[hw][lane] = h2q[(size_t)(lane >> 3) * QT + node * 8 + (lane & 7)];
    __syncthreads();
    float g = bl1[lane];
#pragma unroll
    for (int k = 0; k < HID; ++k) g += h2s[hw][k] * wl1[k * HID + lane];
    float o = fmaxf(g, 0.f) * Wl2[lane];
#pragma unroll
    for (int off = 16; off; off >>= 1) o += __shfl_down(o, off, 32);
    if (lane == 0) out[node] = o + *bl2;
}

extern "C" void kernel_launch(void* const* d_in, const int* in_sizes, int n_in,
                              void* d_out, int out_size, void* d_ws, size_t ws_size,
                              hipStream_t stream) {
    const float* x   = (const float*)d_in[0];
    const int*   e   = (const int*)d_in[1];
    const float* W1  = (const float*)d_in[2];
    const float* b1  = (const float*)d_in[3];
    const float* W2  = (const float*)d_in[4];
    const float* b2  = (const float*)d_in[5];
    const float* Wl1 = (const float*)d_in[6];
    const float* bl1 = (const float*)d_in[7];
    const float* Wl2 = (const float*)d_in[8];
    const float* bl2 = (const float*)d_in[9];
    float* out = (float*)d_out;

    char* w = (char*)d_ws;
    unsigned int*   ebuf   = (unsigned int*)(w + O_EBUF);
    float*          A0     = (float*)(w + O_A0);    // hsq, then hs2q
    float*          A1     = (float*)(w + O_A1);    // h1q, then h2q
    int*            ghist  = (int*)(w + O_GH);
    unsigned short* gh2    = (unsigned short*)(w + O_GH);   // overlays ghist (dead)
    int*            cursors= (int*)(w + O_CUR);
    int*            csr    = (int*)(w + O_CSR);             // overlays cursors (dead)
    int*            rows   = (int*)(w + O_ROWS);
    int*            bstart = (int*)(w + O_BST);
    int*            btot   = (int*)(w + O_BTOT);
    int*            flag   = (int*)(w + O_FLAG);

    const int NB_NODE = N_NODES / 8;          // 12500 exact

    k_detect<<<1, 256, 0, stream>>>((const unsigned int*)e, flag);
    k_hist<<<NBLK, 256, 0, stream>>>(e, flag, ghist);
    k_scan1<<<NBKT, 64, 0, stream>>>(ghist, btot);
    k_scan2<<<1, 1024, 0, stream>>>(btot, bstart);
    k_scan3<<<1, 256, 0, stream>>>(ghist, bstart, cursors);
    k_scatter<<<NBLK, 512, 0, stream>>>(e, flag, ghist, cursors, ebuf);
    k_sort2a<<<NBKT * 4, 512, 0, stream>>>(ebuf, bstart, gh2);
    k_sort2b<<<NBKT * 4, 512, 0, stream>>>(ebuf, bstart, gh2, csr, rows);

    k_gemm1<<<NB_NODE, 256, 0, stream>>>(x, W1, rows, A0);
    for (int q = 0; q < 4; ++q)               // conv1: 4 channel-quarter passes
        k_aggpass<<<NB_NODE, 512, 0, stream>>>(A0 + (size_t)q * QT, csr, rows,
                                               b1 + 8 * q, A1 + (size_t)q * QT);
    k_gemm2<<<NB_NODE, 256, 0, stream>>>(A1, W2, rows, A0);
    for (int q = 0; q < 4; ++q)               // conv2: 4 channel-quarter passes
        k_aggpass<<<NB_NODE, 512, 0, stream>>>(A0 + (size_t)q * QT, csr, rows,
                                               b2 + 8 * q, A1 + (size_t)q * QT);
    k_head<<<NB_NODE, 256, 0, stream>>>(A1, Wl1, bl1, Wl2, bl2, out);
}

// Round 12
// 442.633 us; speedup vs baseline: 1.6405x; 1.6405x over previous
//
#include <hip/hip_runtime.h>

#define N_NODES 100000
#define N_EDGES 6400000
#define IN_CH   128
#define HID     32

#define BKT_SHIFT 9
#define BKT_MASK  511
#define BKT_SZ    512
#define NBKT      196           // ceil(100000/512)
#define NBLK      1024          // histogram/scatter tiles
#define TILE      6250          // 6.4M / 1024 exactly
#define QMAX      8704          // quarter-bucket LDS staging capacity

// ---------- ws layout (bytes) ----------
// [0, 25.6M): ebuf during build; then hs | hs2 after sort2b
#define O_EBUF 0u
#define O_HS   0u
#define O_HS2  12800000u
// ghist int[1024*196]=802,816 (hist->scatter); gh2 ushort overlay (sort2a->b)
#define O_GH   25600000u
// cursors (scan3->scatter) then csr32 (sort2b->aggs) overlay
#define O_CUR  26402816u
#define O_CSR  26402816u        // int[6.4M] -> ends 52,002,816
#define O_ROWS 52002816u        // (N_NODES+1)*4
#define O_BST  52402824u
#define O_BTOT 52403616u
#define O_FLAG 52404400u
// total ~52.40 MB (<= 52.80 MB proven in R1)

// Detect whether edge_index buffer is int64 (high words all zero) or int32.
__global__ void k_detect(const unsigned int* e, int* flag) {
    __shared__ int any;
    if (threadIdx.x == 0) any = 0;
    __syncthreads();
    int acc = 0;
    for (int i = threadIdx.x; i < 4096; i += 256)
        acc |= (e[2 * i + 1] != 0u);
    if (acc) atomicOr(&any, 1);
    __syncthreads();
    if (threadIdx.x == 0) *flag = any ? 0 : 1;   // 1 => int64
}

// Non-temporal streaming edge load (wave-coalesced, read-once). LOADS ONLY.
__device__ __forceinline__ int eload_nt(const int* e, int is64, long long idx) {
    return is64 ? (int)__builtin_nontemporal_load((const long long*)e + idx)
                : __builtin_nontemporal_load(e + (size_t)idx);
}

// Per-tile histogram over destination buckets (LDS int atomics only).
__global__ void k_hist(const int* e, const int* flag, int* ghist) {
    __shared__ int h[NBKT];
    for (int i = threadIdx.x; i < NBKT; i += 256) h[i] = 0;
    __syncthreads();
    int is64 = *flag;
    long long base = (long long)blockIdx.x * TILE;
    for (int k = threadIdx.x; k < TILE; k += 256) {
        int dst = eload_nt(e, is64, (long long)N_EDGES + base + k);
        atomicAdd(&h[dst >> BKT_SHIFT], 1);
    }
    __syncthreads();
    int* g = ghist + blockIdx.x * NBKT;
    for (int i = threadIdx.x; i < NBKT; i += 256) g[i] = h[i];
}

// btot[j] = sum over tiles of ghist[blk][j]; one block per bucket, wave reduce.
__global__ void k_scan1(const int* __restrict__ ghist, int* __restrict__ btot) {
    int j = blockIdx.x;
    int t = threadIdx.x;             // 64 threads
    int s = 0;
    for (int blk = t; blk < NBLK; blk += 64) s += ghist[blk * NBKT + j];
#pragma unroll
    for (int off = 32; off; off >>= 1) s += __shfl_down(s, off, 64);
    if (t == 0) btot[j] = s;
}

__global__ void k_scan2(const int* __restrict__ btot, int* __restrict__ bstart) {
    __shared__ int s[1024];
    int t = threadIdx.x;
    int v = (t < NBKT) ? btot[t] : 0;
    s[t] = v;
    __syncthreads();
    for (int off = 1; off < 1024; off <<= 1) {
        int u = (t >= off) ? s[t - off] : 0;
        __syncthreads();
        s[t] += u;
        __syncthreads();
    }
    if (t < NBKT) bstart[t] = s[t] - v;
    if (t == 0) bstart[NBKT] = N_EDGES;
}

__global__ void k_scan3(const int* __restrict__ ghist, const int* __restrict__ bstart,
                        int* __restrict__ cursors) {
    int j = blockIdx.x * 256 + threadIdx.x;
    if (j >= NBKT) return;
    int run = bstart[j];
    for (int blk = 0; blk < NBLK; ++blk) {
        cursors[blk * NBKT + j] = run;
        run += ghist[blk * NBKT + j];
    }
}

// Scatter: local counting sort in LDS, then burst copy-out (full-line runs).
__launch_bounds__(512)
__global__ void k_scatter(const int* e, const int* flag,
                          const int* __restrict__ ghist, const int* __restrict__ cursors,
                          unsigned int* __restrict__ ebuf) {
    __shared__ unsigned obuf[TILE];          // 25,000 B
    __shared__ unsigned char bid[TILE];      //  6,250 B
    __shared__ int lcur[NBKT];
    __shared__ int gbase[NBKT];
    __shared__ int wsum[8];
    int t = threadIdx.x;
    int blk = blockIdx.x;
    {
        int v = (t < NBKT) ? ghist[blk * NBKT + t] : 0;
        int lane = t & 63, w = t >> 6;
        int p = v;
#pragma unroll
        for (int off = 1; off < 64; off <<= 1) {
            int u = __shfl_up(p, off, 64);
            if (lane >= off) p += u;
        }
        if (lane == 63) wsum[w] = p;
        __syncthreads();
        int woff = 0;
        for (int k = 0; k < w; ++k) woff += wsum[k];
        int excl = woff + p - v;
        if (t < NBKT) {
            lcur[t]  = excl;
            gbase[t] = cursors[blk * NBKT + t] - excl;
        }
    }
    __syncthreads();
    int is64 = *flag;
    long long base = (long long)blk * TILE;
    for (int k = t; k < TILE; k += 512) {
        int src = eload_nt(e, is64, base + k);
        int dst = eload_nt(e, is64, (long long)N_EDGES + base + k);
        int b = dst >> BKT_SHIFT;
        int pos = atomicAdd(&lcur[b], 1);
        obuf[pos] = ((unsigned)src << BKT_SHIFT) | (unsigned)(dst & BKT_MASK);
        bid[pos] = (unsigned char)b;
    }
    __syncthreads();
    for (int i = t; i < TILE; i += 512) {
        int b = bid[i];
        ebuf[gbase[b] + i] = obuf[i];        // consecutive i -> consecutive addr
    }
}

// sort2a: per (bucket, quarter) histogram of dst-local bins -> gh2 (ushort).
__launch_bounds__(512)
__global__ void k_sort2a(const unsigned int* __restrict__ ebuf, const int* __restrict__ bstart,
                         unsigned short* __restrict__ gh2) {
    __shared__ int hist[BKT_SZ];
    int b = blockIdx.x >> 2, q = blockIdx.x & 3;
    int s0 = bstart[b], e0 = bstart[b + 1], len = e0 - s0;
    int lo = s0 + (int)((long long)len * q / 4);
    int hi = s0 + (int)((long long)len * (q + 1) / 4);
    hist[threadIdx.x] = 0;
    __syncthreads();
    for (int i = lo + (int)threadIdx.x; i < hi; i += 512)
        atomicAdd(&hist[__builtin_nontemporal_load(&ebuf[i]) & BKT_MASK], 1);
    __syncthreads();
    gh2[(b * 4 + q) * BKT_SZ + threadIdx.x] = (unsigned short)hist[threadIdx.x];
}

// sort2b: per (bucket, quarter) — scan bucket bins from 4 quarter-hists, then
// LDS counting sort of this quarter + burst copy-out.
__launch_bounds__(512)
__global__ void k_sort2b(const unsigned int* __restrict__ ebuf, const int* __restrict__ bstart,
                         const unsigned short* __restrict__ gh2, int* __restrict__ csr,
                         int* __restrict__ rows) {
    __shared__ unsigned obuf[QMAX];          // 34,816 B
    __shared__ unsigned short bid[QMAX];     // 17,408 B
    __shared__ int lcur[BKT_SZ];             // 2 KB
    __shared__ int gbase[BKT_SZ];            // 2 KB
    __shared__ int wsA[8], wsB[8];
    int b = blockIdx.x >> 2, q = blockIdx.x & 3;
    int s0 = bstart[b], e0 = bstart[b + 1], len = e0 - s0;
    int lo = s0 + (int)((long long)len * q / 4);
    int hi = s0 + (int)((long long)len * (q + 1) / 4);
    int t = threadIdx.x;                     // t == bin id
    int h0 = gh2[(b * 4 + 0) * BKT_SZ + t];
    int h1 = gh2[(b * 4 + 1) * BKT_SZ + t];
    int h2 = gh2[(b * 4 + 2) * BKT_SZ + t];
    int h3 = gh2[(b * 4 + 3) * BKT_SZ + t];
    int tot = h0 + h1 + h2 + h3;
    int hq = (q == 0) ? h0 : (q == 1) ? h1 : (q == 2) ? h2 : h3;
    int lane = t & 63, w = t >> 6;
    int p1 = tot, p2 = hq;
#pragma unroll
    for (int off = 1; off < 64; off <<= 1) {
        int u1 = __shfl_up(p1, off, 64);
        int u2 = __shfl_up(p2, off, 64);
        if (lane >= off) { p1 += u1; p2 += u2; }
    }
    if (lane == 63) { wsA[w] = p1; wsB[w] = p2; }
    __syncthreads();
    int woffA = 0, woffB = 0;
    for (int k = 0; k < w; ++k) { woffA += wsA[k]; woffB += wsB[k]; }
    int binstart = s0 + woffA + p1 - tot;    // bucket-wide bin start
    int lexcl    = woffB + p2 - hq;          // this quarter's local packed offset
    int qs = binstart + ((q > 0) ? h0 : 0) + ((q > 1) ? h1 : 0) + ((q > 2) ? h2 : 0);
    lcur[t]  = lexcl;
    gbase[t] = qs - lexcl;
    int node = b * BKT_SZ + t;
    if (q == 0 && node <= N_NODES) rows[node] = binstart;
    __syncthreads();
    for (int i = lo + t; i < hi; i += 512) {
        unsigned v = __builtin_nontemporal_load(&ebuf[i]);
        int bin = v & BKT_MASK;
        int pos = atomicAdd(&lcur[bin], 1);
        obuf[pos] = v >> BKT_SHIFT;
        bid[pos] = (unsigned short)bin;
    }
    __syncthreads();
    int qlen = hi - lo;
    for (int i = t; i < qlen; i += 512) {
        int bn = bid[i];
        csr[gbase[bn] + i] = (int)obuf[i];   // consecutive i -> consecutive addr
    }
}

// hs[i][c] = dinv[i] * sum_k x[i][k] * W1[k][c]
__launch_bounds__(256)
__global__ void k_gemm1(const float* __restrict__ x, const float* __restrict__ W1,
                        const int* __restrict__ rows, float* __restrict__ hs) {
    __shared__ float w[IN_CH * HID];
    __shared__ float xs[8 * IN_CH];
    for (int i = threadIdx.x; i < IN_CH * HID; i += 256) w[i] = W1[i];
    const float4* xb = (const float4*)(x + (size_t)blockIdx.x * 8 * IN_CH);
    ((float4*)xs)[threadIdx.x] = xb[threadIdx.x];
    __syncthreads();
    int lane = threadIdx.x & 31, hw = threadIdx.x >> 5;
    int node = blockIdx.x * 8 + hw;
    float dv = rsqrtf((float)(rows[node + 1] - rows[node] + 1));
    const float* xr = xs + hw * IN_CH;
    float acc = 0.f;
#pragma unroll
    for (int k = 0; k < IN_CH; ++k) acc += xr[k] * w[k * HID + lane];
    hs[(size_t)node * HID + lane] = acc * dv;
}

// ILP-32 gather loop: aim for ~32 independent row-loads in flight per half-wave.
__device__ __forceinline__ float gather_row(const float* __restrict__ feat,
                                            const int* __restrict__ cs,
                                            int len, int lane, float acc) {
    int j = 0;
    for (; j + 32 <= len; j += 32) {
        int idx[32];
#pragma unroll
        for (int u = 0; u < 32; ++u) idx[u] = cs[j + u];
        float f[32];
#pragma unroll
        for (int u = 0; u < 32; ++u) f[u] = feat[(size_t)idx[u] * HID + lane];
        float s0 = 0.f, s1 = 0.f, s2 = 0.f, s3 = 0.f;
#pragma unroll
        for (int u = 0; u < 8; ++u) {
            s0 += f[u];
            s1 += f[8 + u];
            s2 += f[16 + u];
            s3 += f[24 + u];
        }
        acc += (s0 + s1) + (s2 + s3);
    }
    for (; j + 8 <= len; j += 8) {
        int idx[8];
#pragma unroll
        for (int u = 0; u < 8; ++u) idx[u] = cs[j + u];
        float f[8];
#pragma unroll
        for (int u = 0; u < 8; ++u) f[u] = feat[(size_t)idx[u] * HID + lane];
        acc += ((f[0] + f[1]) + (f[2] + f[3])) + ((f[4] + f[5]) + (f[6] + f[7]));
    }
    for (; j < len; ++j) acc += feat[(size_t)cs[j] * HID + lane];
    return acc;
}

// conv1 aggregation + relu + fused W2 GEMM.
// launch_bounds(256,2): allow high VGPR so all 32 gathers stay in flight.
__launch_bounds__(256, 2)
__global__ void k_agg1(const float* __restrict__ hs, const int* __restrict__ csr,
                       const int* __restrict__ rows, const float* __restrict__ b1,
                       const float* __restrict__ W2, float* __restrict__ hs2) {
    __shared__ float w2[HID * HID];
    __shared__ float h1s[8][HID];
    for (int i = threadIdx.x; i < HID * HID; i += 256) w2[i] = W2[i];
    int lane = threadIdx.x & 31, hw = threadIdx.x >> 5;
    int node = blockIdx.x * 8 + hw;
    int r0 = rows[node], r1 = rows[node + 1];
    float dv = rsqrtf((float)(r1 - r0 + 1));
    float acc = hs[(size_t)node * HID + lane];      // self loop
    acc = gather_row(hs, csr + r0, r1 - r0, lane, acc);
    h1s[hw][lane] = fmaxf(acc * dv + b1[lane], 0.f);
    __syncthreads();
    float g = 0.f;
#pragma unroll
    for (int k = 0; k < HID; ++k) g += h1s[hw][k] * w2[k * HID + lane];
    hs2[(size_t)node * HID + lane] = g * dv;
}

// conv2 aggregation + relu + fused MLP head
__launch_bounds__(256, 2)
__global__ void k_agg2(const float* __restrict__ hs2, const int* __restrict__ csr,
                       const int* __restrict__ rows, const float* __restrict__ b2,
                       const float* __restrict__ Wl1, const float* __restrict__ bl1,
                       const float* __restrict__ Wl2, const float* __restrict__ bl2,
                       float* __restrict__ out) {
    __shared__ float wl1[HID * HID];
    __shared__ float h2s[8][HID];
    for (int i = threadIdx.x; i < HID * HID; i += 256) wl1[i] = Wl1[i];
    int lane = threadIdx.x & 31, hw = threadIdx.x >> 5;
    int node = blockIdx.x * 8 + hw;
    int r0 = rows[node], r1 = rows[node + 1];
    float dv = rsqrtf((float)(r1 - r0 + 1));
    float acc = hs2[(size_t)node * HID + lane];
    acc = gather_row(hs2, csr + r0, r1 - r0, lane, acc);
    float h2 = fmaxf(acc * dv + b2[lane], 0.f);
    h2s[hw][lane] = h2;
    __syncthreads();
    float g = bl1[lane];
#pragma unroll
    for (int k = 0; k < HID; ++k) g += h2s[hw][k] * wl1[k * HID + lane];
    float o = fmaxf(g, 0.f) * Wl2[lane];
#pragma unroll
    for (int off = 16; off; off >>= 1) o += __shfl_down(o, off, 32);
    if (lane == 0) out[node] = o + *bl2;
}

extern "C" void kernel_launch(void* const* d_in, const int* in_sizes, int n_in,
                              void* d_out, int out_size, void* d_ws, size_t ws_size,
                              hipStream_t stream) {
    const float* x   = (const float*)d_in[0];
    const int*   e   = (const int*)d_in[1];
    const float* W1  = (const float*)d_in[2];
    const float* b1  = (const float*)d_in[3];
    const float* W2  = (const float*)d_in[4];
    const float* b2  = (const float*)d_in[5];
    const float* Wl1 = (const float*)d_in[6];
    const float* bl1 = (const float*)d_in[7];
    const float* Wl2 = (const float*)d_in[8];
    const float* bl2 = (const float*)d_in[9];
    float* out = (float*)d_out;

    char* w = (char*)d_ws;
    unsigned int*   ebuf   = (unsigned int*)(w + O_EBUF);
    float*          hs     = (float*)(w + O_HS);
    float*          hs2    = (float*)(w + O_HS2);
    int*            ghist  = (int*)(w + O_GH);
    unsigned short* gh2    = (unsigned short*)(w + O_GH);   // overlays ghist (dead)
    int*            cursors= (int*)(w + O_CUR);
    int*            csr    = (int*)(w + O_CSR);             // overlays cursors (dead)
    int*            rows   = (int*)(w + O_ROWS);
    int*            bstart = (int*)(w + O_BST);
    int*            btot   = (int*)(w + O_BTOT);
    int*            flag   = (int*)(w + O_FLAG);

    const int NB_NODE = N_NODES / 8;          // 12500 exact

    k_detect<<<1, 256, 0, stream>>>((const unsigned int*)e, flag);
    k_hist<<<NBLK, 256, 0, stream>>>(e, flag, ghist);
    k_scan1<<<NBKT, 64, 0, stream>>>(ghist, btot);
    k_scan2<<<1, 1024, 0, stream>>>(btot, bstart);
    k_scan3<<<1, 256, 0, stream>>>(ghist, bstart, cursors);
    k_scatter<<<NBLK, 512, 0, stream>>>(e, flag, ghist, cursors, ebuf);
    k_sort2a<<<NBKT * 4, 512, 0, stream>>>(ebuf, bstart, gh2);
    k_sort2b<<<NBKT * 4, 512, 0, stream>>>(ebuf, bstart, gh2, csr, rows);

    k_gemm1<<<NB_NODE, 256, 0, stream>>>(x, W1, rows, hs);
    k_agg1<<<NB_NODE, 256, 0, stream>>>(hs, csr, rows, b1, W2, hs2);
    k_agg2<<<NB_NODE, 256, 0, stream>>>(hs2, csr, rows, b2,
                                        Wl1, bl1, Wl2, bl2, out);
}

// Round 13
// 373.609 us; speedup vs baseline: 1.9435x; 1.1847x over previous
//
#include <hip/hip_runtime.h>

#define N_NODES 100000
#define N_EDGES 6400000
#define IN_CH   128
#define HID     32

#define BKT_SHIFT 9
#define BKT_MASK  511
#define BKT_SZ    512
#define NBKT      196           // ceil(100000/512)
#define NBLK      1024          // histogram/scatter tiles
#define TILE      6250          // 6.4M / 1024 exactly
#define QMAX      8704          // quarter-bucket LDS staging capacity

// ---------- ws layout (bytes) ----------
// [0, 25.6M): ebuf during build; then hs | hs2 after sort2b
#define O_EBUF 0u
#define O_HS   0u
#define O_HS2  12800000u
// ghist int[1024*196]=802,816 (hist->scatter); gh2 ushort overlay (sort2a->b)
#define O_GH   25600000u
// cursors (scan3->scatter) then csr32 (sort2b->aggs) overlay
#define O_CUR  26402816u
#define O_CSR  26402816u        // int[6.4M] -> ends 52,002,816
#define O_ROWS 52002816u        // (N_NODES+1)*4
#define O_BST  52402824u
#define O_BTOT 52403616u
#define O_FLAG 52404400u
// total ~52.40 MB (<= 52.80 MB proven in R1)

// Detect whether edge_index buffer is int64 (high words all zero) or int32.
__global__ void k_detect(const unsigned int* e, int* flag) {
    __shared__ int any;
    if (threadIdx.x == 0) any = 0;
    __syncthreads();
    int acc = 0;
    for (int i = threadIdx.x; i < 4096; i += 256)
        acc |= (e[2 * i + 1] != 0u);
    if (acc) atomicOr(&any, 1);
    __syncthreads();
    if (threadIdx.x == 0) *flag = any ? 0 : 1;   // 1 => int64
}

// Non-temporal streaming edge load (wave-coalesced, read-once). LOADS ONLY.
__device__ __forceinline__ int eload_nt(const int* e, int is64, long long idx) {
    return is64 ? (int)__builtin_nontemporal_load((const long long*)e + idx)
                : __builtin_nontemporal_load(e + (size_t)idx);
}

// Per-tile histogram over destination buckets (LDS int atomics only).
__global__ void k_hist(const int* e, const int* flag, int* ghist) {
    __shared__ int h[NBKT];
    for (int i = threadIdx.x; i < NBKT; i += 256) h[i] = 0;
    __syncthreads();
    int is64 = *flag;
    long long base = (long long)blockIdx.x * TILE;
    for (int k = threadIdx.x; k < TILE; k += 256) {
        int dst = eload_nt(e, is64, (long long)N_EDGES + base + k);
        atomicAdd(&h[dst >> BKT_SHIFT], 1);
    }
    __syncthreads();
    int* g = ghist + blockIdx.x * NBKT;
    for (int i = threadIdx.x; i < NBKT; i += 256) g[i] = h[i];
}

// btot[j] = sum over tiles of ghist[blk][j]; one block per bucket, wave reduce.
__global__ void k_scan1(const int* __restrict__ ghist, int* __restrict__ btot) {
    int j = blockIdx.x;
    int t = threadIdx.x;             // 64 threads
    int s = 0;
    for (int blk = t; blk < NBLK; blk += 64) s += ghist[blk * NBKT + j];
#pragma unroll
    for (int off = 32; off; off >>= 1) s += __shfl_down(s, off, 64);
    if (t == 0) btot[j] = s;
}

__global__ void k_scan2(const int* __restrict__ btot, int* __restrict__ bstart) {
    __shared__ int s[1024];
    int t = threadIdx.x;
    int v = (t < NBKT) ? btot[t] : 0;
    s[t] = v;
    __syncthreads();
    for (int off = 1; off < 1024; off <<= 1) {
        int u = (t >= off) ? s[t - off] : 0;
        __syncthreads();
        s[t] += u;
        __syncthreads();
    }
    if (t < NBKT) bstart[t] = s[t] - v;
    if (t == 0) bstart[NBKT] = N_EDGES;
}

__global__ void k_scan3(const int* __restrict__ ghist, const int* __restrict__ bstart,
                        int* __restrict__ cursors) {
    int j = blockIdx.x * 256 + threadIdx.x;
    if (j >= NBKT) return;
    int run = bstart[j];
    for (int blk = 0; blk < NBLK; ++blk) {
        cursors[blk * NBKT + j] = run;
        run += ghist[blk * NBKT + j];
    }
}

// Scatter: local counting sort in LDS, then burst copy-out (full-line runs).
__launch_bounds__(512)
__global__ void k_scatter(const int* e, const int* flag,
                          const int* __restrict__ ghist, const int* __restrict__ cursors,
                          unsigned int* __restrict__ ebuf) {
    __shared__ unsigned obuf[TILE];          // 25,000 B
    __shared__ unsigned char bid[TILE];      //  6,250 B
    __shared__ int lcur[NBKT];
    __shared__ int gbase[NBKT];
    __shared__ int wsum[8];
    int t = threadIdx.x;
    int blk = blockIdx.x;
    {
        int v = (t < NBKT) ? ghist[blk * NBKT + t] : 0;
        int lane = t & 63, w = t >> 6;
        int p = v;
#pragma unroll
        for (int off = 1; off < 64; off <<= 1) {
            int u = __shfl_up(p, off, 64);
            if (lane >= off) p += u;
        }
        if (lane == 63) wsum[w] = p;
        __syncthreads();
        int woff = 0;
        for (int k = 0; k < w; ++k) woff += wsum[k];
        int excl = woff + p - v;
        if (t < NBKT) {
            lcur[t]  = excl;
            gbase[t] = cursors[blk * NBKT + t] - excl;
        }
    }
    __syncthreads();
    int is64 = *flag;
    long long base = (long long)blk * TILE;
    for (int k = t; k < TILE; k += 512) {
        int src = eload_nt(e, is64, base + k);
        int dst = eload_nt(e, is64, (long long)N_EDGES + base + k);
        int b = dst >> BKT_SHIFT;
        int pos = atomicAdd(&lcur[b], 1);
        obuf[pos] = ((unsigned)src << BKT_SHIFT) | (unsigned)(dst & BKT_MASK);
        bid[pos] = (unsigned char)b;
    }
    __syncthreads();
    for (int i = t; i < TILE; i += 512) {
        int b = bid[i];
        ebuf[gbase[b] + i] = obuf[i];        // consecutive i -> consecutive addr
    }
}

// sort2a: per (bucket, quarter) histogram of dst-local bins -> gh2 (ushort).
__launch_bounds__(512)
__global__ void k_sort2a(const unsigned int* __restrict__ ebuf, const int* __restrict__ bstart,
                         unsigned short* __restrict__ gh2) {
    __shared__ int hist[BKT_SZ];
    int b = blockIdx.x >> 2, q = blockIdx.x & 3;
    int s0 = bstart[b], e0 = bstart[b + 1], len = e0 - s0;
    int lo = s0 + (int)((long long)len * q / 4);
    int hi = s0 + (int)((long long)len * (q + 1) / 4);
    hist[threadIdx.x] = 0;
    __syncthreads();
    for (int i = lo + (int)threadIdx.x; i < hi; i += 512)
        atomicAdd(&hist[__builtin_nontemporal_load(&ebuf[i]) & BKT_MASK], 1);
    __syncthreads();
    gh2[(b * 4 + q) * BKT_SZ + threadIdx.x] = (unsigned short)hist[threadIdx.x];
}

// sort2b: per (bucket, quarter) — scan bucket bins from 4 quarter-hists, then
// LDS counting sort of this quarter + burst copy-out.
__launch_bounds__(512)
__global__ void k_sort2b(const unsigned int* __restrict__ ebuf, const int* __restrict__ bstart,
                         const unsigned short* __restrict__ gh2, int* __restrict__ csr,
                         int* __restrict__ rows) {
    __shared__ unsigned obuf[QMAX];          // 34,816 B
    __shared__ unsigned short bid[QMAX];     // 17,408 B
    __shared__ int lcur[BKT_SZ];             // 2 KB
    __shared__ int gbase[BKT_SZ];            // 2 KB
    __shared__ int wsA[8], wsB[8];
    int b = blockIdx.x >> 2, q = blockIdx.x & 3;
    int s0 = bstart[b], e0 = bstart[b + 1], len = e0 - s0;
    int lo = s0 + (int)((long long)len * q / 4);
    int hi = s0 + (int)((long long)len * (q + 1) / 4);
    int t = threadIdx.x;                     // t == bin id
    int h0 = gh2[(b * 4 + 0) * BKT_SZ + t];
    int h1 = gh2[(b * 4 + 1) * BKT_SZ + t];
    int h2 = gh2[(b * 4 + 2) * BKT_SZ + t];
    int h3 = gh2[(b * 4 + 3) * BKT_SZ + t];
    int tot = h0 + h1 + h2 + h3;
    int hq = (q == 0) ? h0 : (q == 1) ? h1 : (q == 2) ? h2 : h3;
    int lane = t & 63, w = t >> 6;
    int p1 = tot, p2 = hq;
#pragma unroll
    for (int off = 1; off < 64; off <<= 1) {
        int u1 = __shfl_up(p1, off, 64);
        int u2 = __shfl_up(p2, off, 64);
        if (lane >= off) { p1 += u1; p2 += u2; }
    }
    if (lane == 63) { wsA[w] = p1; wsB[w] = p2; }
    __syncthreads();
    int woffA = 0, woffB = 0;
    for (int k = 0; k < w; ++k) { woffA += wsA[k]; woffB += wsB[k]; }
    int binstart = s0 + woffA + p1 - tot;    // bucket-wide bin start
    int lexcl    = woffB + p2 - hq;          // this quarter's local packed offset
    int qs = binstart + ((q > 0) ? h0 : 0) + ((q > 1) ? h1 : 0) + ((q > 2) ? h2 : 0);
    lcur[t]  = lexcl;
    gbase[t] = qs - lexcl;
    int node = b * BKT_SZ + t;
    if (q == 0 && node <= N_NODES) rows[node] = binstart;
    __syncthreads();
    for (int i = lo + t; i < hi; i += 512) {
        unsigned v = __builtin_nontemporal_load(&ebuf[i]);
        int bin = v & BKT_MASK;
        int pos = atomicAdd(&lcur[bin], 1);
        obuf[pos] = v >> BKT_SHIFT;
        bid[pos] = (unsigned short)bin;
    }
    __syncthreads();
    int qlen = hi - lo;
    for (int i = t; i < qlen; i += 512) {
        int bn = bid[i];
        csr[gbase[bn] + i] = (int)obuf[i];   // consecutive i -> consecutive addr
    }
}

// hs[i][c] = dinv[i] * sum_k x[i][k] * W1[k][c]
__launch_bounds__(256)
__global__ void k_gemm1(const float* __restrict__ x, const float* __restrict__ W1,
                        const int* __restrict__ rows, float* __restrict__ hs) {
    __shared__ float w[IN_CH * HID];
    __shared__ float xs[8 * IN_CH];
    for (int i = threadIdx.x; i < IN_CH * HID; i += 256) w[i] = W1[i];
    const float4* xb = (const float4*)(x + (size_t)blockIdx.x * 8 * IN_CH);
    ((float4*)xs)[threadIdx.x] = xb[threadIdx.x];
    __syncthreads();
    int lane = threadIdx.x & 31, hw = threadIdx.x >> 5;
    int node = blockIdx.x * 8 + hw;
    float dv = rsqrtf((float)(rows[node + 1] - rows[node] + 1));
    const float* xr = xs + hw * IN_CH;
    float acc = 0.f;
#pragma unroll
    for (int k = 0; k < IN_CH; ++k) acc += xr[k] * w[k * HID + lane];
    hs[(size_t)node * HID + lane] = acc * dv;
}

// ILP-16 gather loop: 16 independent row-loads in flight per half-wave.
__device__ __forceinline__ float gather_row(const float* __restrict__ feat,
                                            const int* __restrict__ cs,
                                            int len, int lane, float acc) {
    int j = 0;
    for (; j + 16 <= len; j += 16) {
        int idx[16];
#pragma unroll
        for (int u = 0; u < 16; ++u) idx[u] = cs[j + u];
        float f[16];
#pragma unroll
        for (int u = 0; u < 16; ++u) f[u] = feat[(size_t)idx[u] * HID + lane];
        acc += (((f[0] + f[1]) + (f[2] + f[3])) + ((f[4] + f[5]) + (f[6] + f[7])))
             + (((f[8] + f[9]) + (f[10] + f[11])) + ((f[12] + f[13]) + (f[14] + f[15])));
    }
    for (; j + 8 <= len; j += 8) {
        int idx[8];
#pragma unroll
        for (int u = 0; u < 8; ++u) idx[u] = cs[j + u];
        float f[8];
#pragma unroll
        for (int u = 0; u < 8; ++u) f[u] = feat[(size_t)idx[u] * HID + lane];
        acc += ((f[0] + f[1]) + (f[2] + f[3])) + ((f[4] + f[5]) + (f[6] + f[7]));
    }
    for (; j < len; ++j) acc += feat[(size_t)cs[j] * HID + lane];
    return acc;
}

// conv1 aggregation + relu + fused W2 GEMM
__launch_bounds__(256)
__global__ void k_agg1(const float* __restrict__ hs, const int* __restrict__ csr,
                       const int* __restrict__ rows, const float* __restrict__ b1,
                       const float* __restrict__ W2, float* __restrict__ hs2) {
    __shared__ float w2[HID * HID];
    __shared__ float h1s[8][HID];
    for (int i = threadIdx.x; i < HID * HID; i += 256) w2[i] = W2[i];
    int lane = threadIdx.x & 31, hw = threadIdx.x >> 5;
    int node = blockIdx.x * 8 + hw;
    int r0 = rows[node], r1 = rows[node + 1];
    float dv = rsqrtf((float)(r1 - r0 + 1));
    float acc = hs[(size_t)node * HID + lane];      // self loop
    acc = gather_row(hs, csr + r0, r1 - r0, lane, acc);
    h1s[hw][lane] = fmaxf(acc * dv + b1[lane], 0.f);
    __syncthreads();
    float g = 0.f;
#pragma unroll
    for (int k = 0; k < HID; ++k) g += h1s[hw][k] * w2[k * HID + lane];
    hs2[(size_t)node * HID + lane] = g * dv;
}

// conv2 aggregation + relu + fused MLP head
__launch_bounds__(256)
__global__ void k_agg2(const float* __restrict__ hs2, const int* __restrict__ csr,
                       const int* __restrict__ rows, const float* __restrict__ b2,
                       const float* __restrict__ Wl1, const float* __restrict__ bl1,
                       const float* __restrict__ Wl2, const float* __restrict__ bl2,
                       float* __restrict__ out) {
    __shared__ float wl1[HID * HID];
    __shared__ float h2s[8][HID];
    for (int i = threadIdx.x; i < HID * HID; i += 256) wl1[i] = Wl1[i];
    int lane = threadIdx.x & 31, hw = threadIdx.x >> 5;
    int node = blockIdx.x * 8 + hw;
    int r0 = rows[node], r1 = rows[node + 1];
    float dv = rsqrtf((float)(r1 - r0 + 1));
    float acc = hs2[(size_t)node * HID + lane];
    acc = gather_row(hs2, csr + r0, r1 - r0, lane, acc);
    float h2 = fmaxf(acc * dv + b2[lane], 0.f);
    h2s[hw][lane] = h2;
    __syncthreads();
    float g = bl1[lane];
#pragma unroll
    for (int k = 0; k < HID; ++k) g += h2s[hw][k] * wl1[k * HID + lane];
    float o = fmaxf(g, 0.f) * Wl2[lane];
#pragma unroll
    for (int off = 16; off; off >>= 1) o += __shfl_down(o, off, 32);
    if (lane == 0) out[node] = o + *bl2;
}

extern "C" void kernel_launch(void* const* d_in, const int* in_sizes, int n_in,
                              void* d_out, int out_size, void* d_ws, size_t ws_size,
                              hipStream_t stream) {
    const float* x   = (const float*)d_in[0];
    const int*   e   = (const int*)d_in[1];
    const float* W1  = (const float*)d_in[2];
    const float* b1  = (const float*)d_in[3];
    const float* W2  = (const float*)d_in[4];
    const float* b2  = (const float*)d_in[5];
    const float* Wl1 = (const float*)d_in[6];
    const float* bl1 = (const float*)d_in[7];
    const float* Wl2 = (const float*)d_in[8];
    const float* bl2 = (const float*)d_in[9];
    float* out = (float*)d_out;

    char* w = (char*)d_ws;
    unsigned int*   ebuf   = (unsigned int*)(w + O_EBUF);
    float*          hs     = (float*)(w + O_HS);
    float*          hs2    = (float*)(w + O_HS2);
    int*            ghist  = (int*)(w + O_GH);
    unsigned short* gh2    = (unsigned short*)(w + O_GH);   // overlays ghist (dead)
    int*            cursors= (int*)(w + O_CUR);
    int*            csr    = (int*)(w + O_CSR);             // overlays cursors (dead)
    int*            rows   = (int*)(w + O_ROWS);
    int*            bstart = (int*)(w + O_BST);
    int*            btot   = (int*)(w + O_BTOT);
    int*            flag   = (int*)(w + O_FLAG);

    const int NB_NODE = N_NODES / 8;          // 12500 exact

    k_detect<<<1, 256, 0, stream>>>((const unsigned int*)e, flag);
    k_hist<<<NBLK, 256, 0, stream>>>(e, flag, ghist);
    k_scan1<<<NBKT, 64, 0, stream>>>(ghist, btot);
    k_scan2<<<1, 1024, 0, stream>>>(btot, bstart);
    k_scan3<<<1, 256, 0, stream>>>(ghist, bstart, cursors);
    k_scatter<<<NBLK, 512, 0, stream>>>(e, flag, ghist, cursors, ebuf);
    k_sort2a<<<NBKT * 4, 512, 0, stream>>>(ebuf, bstart, gh2);
    k_sort2b<<<NBKT * 4, 512, 0, stream>>>(ebuf, bstart, gh2, csr, rows);

    k_gemm1<<<NB_NODE, 256, 0, stream>>>(x, W1, rows, hs);
    k_agg1<<<NB_NODE, 256, 0, stream>>>(hs, csr, rows, b1, W2, hs2);
    k_agg2<<<NB_NODE, 256, 0, stream>>>(hs2, csr, rows, b2,
                                        Wl1, bl1, Wl2, bl2, out);
}